// Round 10
// baseline (149.231 us; speedup 1.0000x reference)
//
#include <hip/hip_runtime.h>

#define KOBJ  128
#define QMIN  0.5f
#define SB    1.0f
#define BDIM  256
#define NSCB  128           // scan blocks per batch element
#define BATCH 8
#define PPB   256           // points per pairs-block (1 per thread)
#define REPS  16            // diagnostic amplification factor

typedef unsigned long long u64;
typedef unsigned int u32;

// ---- workspace layout (bytes); NO zero-init required (plain stores only) ----
// 0       : u64  pkey [BATCH*NSCB][KOBJ]  1048576 B
// 1048576 : f32  nsp  [BATCH*NSCB]           4096 B
// 1052672 : u32  ncp  [BATCH*NSCB]           4096 B
// 1056768 : f4   tab  [BATCH][KOBJ]         16384 B  {-2x, -2y, x^2+y^2, q*present}
// 1073152 : f32  qsum [BATCH]                  32 B
// total 1073184 B

__device__ __forceinline__ float waveRedF(float v) {
    #pragma unroll
    for (int o = 32; o; o >>= 1) v += __shfl_down(v, o, 64);
    return v;
}
__device__ __forceinline__ u32 waveRedU(u32 v) {
    #pragma unroll
    for (int o = 32; o; o >>= 1) v += __shfl_down(v, o, 64);
    return v;
}

// ---------- dispatch 1: argmax scan (x16 amplified for profiling) ----------
__global__ void __launch_bounds__(BDIM)
oc_scan_x16(const float* __restrict__ beta, const int* __restrict__ t_idx,
            u64* __restrict__ pkey, float* __restrict__ nsp, u32* __restrict__ ncp,
            float* __restrict__ out, int N) {
    const int tid = threadIdx.x;
    const int b   = blockIdx.y;
    const int sub = blockIdx.x;
    const int bid = b * NSCB + sub;
    const int chunk = (N + NSCB - 1) / NSCB;
    const int n0 = sub * chunk;
    const int n1 = min(n0 + chunk, N);

    if (bid == 0 && tid == 0) out[0] = 0.f;      // fresh accumulator each call

    __shared__ u64 skey[KOBJ];
    if (tid < KOBJ) skey[tid] = 0ull;
    __syncthreads();

    float ns = 0.f;
    u32 nc = 0u;
    #pragma unroll 1
    for (int rep = 0; rep < REPS; ++rep) {       // idempotent amplification
        for (int n = n0 + tid; n < n1; n += BDIM) {
            const float bc = fminf(fmaxf(beta[(size_t)b * N + n], 1e-6f), 1.0f - 1e-5f);
            const int t = t_idx[(size_t)b * N + n];
            const u64 kk = ((u64)__float_as_uint(bc) << 32) | (u64)(~(u32)n);
            atomicMax(&skey[t], kk);             // LDS atomic, idempotent across reps
            if (rep == 0 && t == 0) { ns += bc; nc++; }   // uniform rep-branch
        }
    }
    __syncthreads();
    if (tid < KOBJ) pkey[(size_t)bid * KOBJ + tid] = skey[tid];

    ns = waveRedF(ns);
    nc = waveRedU(nc);
    __shared__ float s_ns[BDIM / 64];
    __shared__ u32   s_nc[BDIM / 64];
    if ((tid & 63) == 0) { s_ns[tid >> 6] = ns; s_nc[tid >> 6] = nc; }
    __syncthreads();
    if (tid == 0) {
        float a = 0.f; u32 c = 0u;
        #pragma unroll
        for (int w = 0; w < BDIM / 64; ++w) { a += s_ns[w]; c += s_nc[w]; }
        nsp[bid] = a; ncp[bid] = c;
    }
}

// ---------- dispatch 2: collapse partials -> expansion table (unchanged) ----------
__global__ void __launch_bounds__(KOBJ)
oc_reduce(const float* __restrict__ cc, const u64* __restrict__ pkey,
          const float* __restrict__ nsp, const u32* __restrict__ ncp,
          float4* __restrict__ tab, float* __restrict__ qsum,
          float* __restrict__ out, int N) {
    const int b = blockIdx.x;
    const int k = threadIdx.x;          // 128 threads

    u64 kv = 0ull;
    #pragma unroll 8
    for (int s = 0; s < NSCB; ++s) {
        const u64 v = pkey[(size_t)(b * NSCB + s) * KOBJ + k];
        kv = v > kv ? v : kv;
    }
    const bool present = (kv != 0ull) && (k > 0);
    float x = 0.f, y = 0.f, qv = 0.f, lb = 0.f;
    u32 pc = 0u;
    if (kv != 0ull) {
        const u32 na = ~(u32)(kv & 0xFFFFFFFFull);
        const float ba = __uint_as_float((u32)(kv >> 32));
        const float2 xy = *(const float2*)&cc[((size_t)b * N + na) * 2];
        x = xy.x; y = xy.y;
        const float a = atanhf(ba / 1.002f);
        qv = a * a + QMIN;
        if (present) { lb = 1.f - ba; pc = 1u; }
    }
    const float qe = present ? qv : 0.f;
    tab[(size_t)b * KOBJ + k] =
        make_float4(-2.f * x, -2.f * y, fmaf(x, x, y * y), qe);

    float ns = nsp[b * NSCB + k];
    u32   nc = ncp[b * NSCB + k];

    lb = waveRedF(lb);  pc = waveRedU(pc);
    ns = waveRedF(ns);  nc = waveRedU(nc);
    float qs = waveRedF(qe);
    __shared__ float s_lb[2], s_ns[2], s_qs[2];
    __shared__ u32   s_pc[2], s_nc[2];
    const int wv = k >> 6;
    if ((k & 63) == 0) { s_lb[wv] = lb; s_pc[wv] = pc; s_ns[wv] = ns; s_nc[wv] = nc; s_qs[wv] = qs; }
    __syncthreads();
    if (k == 0) {
        const float L = s_lb[0] + s_lb[1];
        const u32   P = s_pc[0] + s_pc[1];
        const float A = s_ns[0] + s_ns[1];
        const u32   C = s_nc[0] + s_nc[1];
        qsum[b] = s_qs[0] + s_qs[1];
        const float terms = L / (float)max(P, 1u) + SB * A / (float)max(C, 1u);
        atomicAdd(out, terms * (1.f / (float)BATCH));
    }
}

// ---------- dispatch 3: pair potentials (x16 amplified for profiling) ----------
__global__ void __launch_bounds__(PPB)
oc_pairs_x16(const float* __restrict__ cc, const float* __restrict__ beta,
             const int* __restrict__ t_idx,
             const float4* __restrict__ tab, const float* __restrict__ qsum,
             float* __restrict__ out, int N, float invNB) {
    const int tid = threadIdx.x;
    const int b   = blockIdx.y;
    const int sub = blockIdx.x;
    const int n   = sub * PPB + tid;

    const float4* __restrict__ T = tab + (size_t)b * KOBJ;   // block-uniform base

    float acc_tot = 0.f;
    if (n < N) {
        const float2 xy = *(const float2*)&cc[((size_t)b * N + n) * 2];
        const float bc = fminf(fmaxf(beta[(size_t)b * N + n], 1e-6f), 1.0f - 1e-5f);
        const int t = t_idx[(size_t)b * N + n];
        const float a = atanhf(bc / 1.002f);
        const float qn = a * a + QMIN;
        const float pn2e = fmaf(xy.x, xy.x, fmaf(xy.y, xy.y, 1e-6f));

        float accs = 0.f;
        #pragma unroll 1
        for (int rep = 0; rep < REPS; ++rep) {
            float px = xy.x, py = xy.y, pz = pn2e;
            asm volatile("" : "+v"(px), "+v"(py), "+v"(pz));   // defeat LICM/GVN
            float acc = 0.f;
            #pragma unroll 8
            for (int k = 0; k < KOBJ; ++k) {
                const float4 Tk = T[k];
                const float d2e = fmaf(Tk.x, px, fmaf(Tk.y, py, Tk.z + pz));
                const float d   = __builtin_amdgcn_sqrtf(d2e);
                acc = fmaf(Tk.w, fminf(d, 1.f), acc);
            }
            accs += acc;
        }
        const float acc = accs * (1.f / (float)REPS);          // exact pow-2 scale

        const float4 Tt = T[t];
        const float d2et = fmaf(Tt.x, xy.x, fmaf(Tt.y, xy.y, Tt.z + pn2e));
        const float dt   = __builtin_amdgcn_sqrtf(d2et);
        const float point = qsum[b] - acc
                          + Tt.w * ((d2et - 1e-6f) - 1.f + fminf(dt, 1.f));
        acc_tot = point * qn;
    }

    acc_tot = waveRedF(acc_tot);
    __shared__ float s_a[PPB / 64];
    if ((tid & 63) == 0) s_a[tid >> 6] = acc_tot;
    __syncthreads();
    if (tid == 0) {
        float s = 0.f;
        #pragma unroll
        for (int w = 0; w < PPB / 64; ++w) s += s_a[w];
        atomicAdd(out, s * invNB);
    }
}

extern "C" void kernel_launch(void* const* d_in, const int* in_sizes, int n_in,
                              void* d_out, int out_size, void* d_ws, size_t ws_size,
                              hipStream_t stream) {
    const float* cc   = (const float*)d_in[0];   // (B,N,2) f32
    const float* beta = (const float*)d_in[1];   // (B,N)   f32
    const int*   tix  = (const int*)d_in[2];     // (B,N)   i32
    float* out = (float*)d_out;
    const int N = in_sizes[1] / BATCH;

    char* ws = (char*)d_ws;
    u64*    pkey = (u64*)(ws + 0);
    float*  nsp  = (float*)(ws + 1048576);
    u32*    ncp  = (u32*)(ws + 1052672);
    float4* tab  = (float4*)(ws + 1056768);
    float*  qsum = (float*)(ws + 1073152);

    const int nppb = (N + PPB - 1) / PPB;        // pairs blocks per batch
    const float invNB = 1.f / ((float)N * (float)BATCH);

    oc_scan_x16 <<<dim3(NSCB, BATCH), BDIM, 0, stream>>>(beta, tix, pkey, nsp, ncp, out, N);
    oc_reduce   <<<dim3(BATCH), KOBJ, 0, stream>>>(cc, pkey, nsp, ncp, tab, qsum, out, N);
    oc_pairs_x16<<<dim3(nppb, BATCH), PPB, 0, stream>>>(cc, beta, tix, tab, qsum, out, N, invNB);
}

// Round 11
// 39.159 us; speedup vs baseline: 3.8109x; 3.8109x over previous
//
#include <hip/hip_runtime.h>

#define KOBJ  128
#define QMIN  0.5f
#define SB    1.0f
#define BDIM  256
#define NSCB  128           // scan blocks per batch element
#define BATCH 8
#define PPB   256           // points per pairs-block (1 per thread)

typedef unsigned long long u64;
typedef unsigned int u32;

// ---- workspace layout (bytes); NO zero-init required (plain stores only) ----
// 0       : u64  pkey [BATCH*NSCB][KOBJ]  1048576 B
// 1048576 : f32  nsp  [BATCH*NSCB]           4096 B
// 1052672 : u32  ncp  [BATCH*NSCB]           4096 B
// 1056768 : f4   tab  [BATCH][KOBJ]         16384 B  {-2x, -2y, x^2+y^2, q*present}
// 1073152 : f32  qsum [BATCH]                  32 B
// total 1073184 B

__device__ __forceinline__ float waveRedF(float v) {
    #pragma unroll
    for (int o = 32; o; o >>= 1) v += __shfl_down(v, o, 64);
    return v;
}
__device__ __forceinline__ u32 waveRedU(u32 v) {
    #pragma unroll
    for (int o = 32; o; o >>= 1) v += __shfl_down(v, o, 64);
    return v;
}

// ---------- dispatch 1: per-block argmax scan + noise partials; zero out[0] ----------
__global__ void __launch_bounds__(BDIM)
oc_scan(const float* __restrict__ beta, const int* __restrict__ t_idx,
        u64* __restrict__ pkey, float* __restrict__ nsp, u32* __restrict__ ncp,
        float* __restrict__ out, int N) {
    const int tid = threadIdx.x;
    const int b   = blockIdx.y;
    const int sub = blockIdx.x;
    const int bid = b * NSCB + sub;
    const int chunk = (N + NSCB - 1) / NSCB;
    const int n0 = sub * chunk;
    const int n1 = min(n0 + chunk, N);

    if (bid == 0 && tid == 0) out[0] = 0.f;      // fresh accumulator each call

    __shared__ u64 skey[KOBJ];
    if (tid < KOBJ) skey[tid] = 0ull;
    __syncthreads();

    float ns = 0.f;
    u32 nc = 0u;
    for (int n = n0 + tid; n < n1; n += BDIM) {
        const float bc = fminf(fmaxf(beta[(size_t)b * N + n], 1e-6f), 1.0f - 1e-5f);
        const int t = t_idx[(size_t)b * N + n];
        const u64 kk = ((u64)__float_as_uint(bc) << 32) | (u64)(~(u32)n);  // ties -> min n
        atomicMax(&skey[t], kk);                                            // LDS atomic
        if (t == 0) { ns += bc; nc++; }
    }
    __syncthreads();
    if (tid < KOBJ) pkey[(size_t)bid * KOBJ + tid] = skey[tid];

    ns = waveRedF(ns);
    nc = waveRedU(nc);
    __shared__ float s_ns[BDIM / 64];
    __shared__ u32   s_nc[BDIM / 64];
    if ((tid & 63) == 0) { s_ns[tid >> 6] = ns; s_nc[tid >> 6] = nc; }
    __syncthreads();
    if (tid == 0) {
        float a = 0.f; u32 c = 0u;
        #pragma unroll
        for (int w = 0; w < BDIM / 64; ++w) { a += s_ns[w]; c += s_nc[w]; }
        nsp[bid] = a; ncp[bid] = c;
    }
}

// ---------- dispatch 2: collapse partials -> expansion table; add (L_beta+L_noise)/B ----------
__global__ void __launch_bounds__(KOBJ)
oc_reduce(const float* __restrict__ cc, const u64* __restrict__ pkey,
          const float* __restrict__ nsp, const u32* __restrict__ ncp,
          float4* __restrict__ tab, float* __restrict__ qsum,
          float* __restrict__ out, int N) {
    const int b = blockIdx.x;
    const int k = threadIdx.x;          // 128 threads

    u64 kv = 0ull;
    #pragma unroll 8
    for (int s = 0; s < NSCB; ++s) {
        const u64 v = pkey[(size_t)(b * NSCB + s) * KOBJ + k];
        kv = v > kv ? v : kv;
    }
    const bool present = (kv != 0ull) && (k > 0);
    float x = 0.f, y = 0.f, qv = 0.f, lb = 0.f;
    u32 pc = 0u;
    if (kv != 0ull) {
        const u32 na = ~(u32)(kv & 0xFFFFFFFFull);
        const float ba = __uint_as_float((u32)(kv >> 32));
        const float2 xy = *(const float2*)&cc[((size_t)b * N + na) * 2];
        x = xy.x; y = xy.y;
        const float a = atanhf(ba / 1.002f);
        qv = a * a + QMIN;
        if (present) { lb = 1.f - ba; pc = 1u; }
    }
    const float qe = present ? qv : 0.f;
    // expansion-form table: d2 = (x^2+y^2) + |p|^2 + (-2x)*px + (-2y)*py
    tab[(size_t)b * KOBJ + k] =
        make_float4(-2.f * x, -2.f * y, fmaf(x, x, y * y), qe);

    float ns = nsp[b * NSCB + k];
    u32   nc = ncp[b * NSCB + k];

    lb = waveRedF(lb);  pc = waveRedU(pc);
    ns = waveRedF(ns);  nc = waveRedU(nc);
    float qs = waveRedF(qe);
    __shared__ float s_lb[2], s_ns[2], s_qs[2];
    __shared__ u32   s_pc[2], s_nc[2];
    const int wv = k >> 6;
    if ((k & 63) == 0) { s_lb[wv] = lb; s_pc[wv] = pc; s_ns[wv] = ns; s_nc[wv] = nc; s_qs[wv] = qs; }
    __syncthreads();
    if (k == 0) {
        const float L = s_lb[0] + s_lb[1];
        const u32   P = s_pc[0] + s_pc[1];
        const float A = s_ns[0] + s_ns[1];
        const u32   C = s_nc[0] + s_nc[1];
        qsum[b] = s_qs[0] + s_qs[1];
        const float terms = L / (float)max(P, 1u) + SB * A / (float)max(C, 1u);
        atomicAdd(out, terms * (1.f / (float)BATCH));   // out zeroed in dispatch 1
    }
}

// ---------- dispatch 3: O(N*K) pair potentials; 2-acc ILP k-loop ----------
__global__ void __launch_bounds__(PPB)
oc_pairs(const float* __restrict__ cc, const float* __restrict__ beta,
         const int* __restrict__ t_idx,
         const float4* __restrict__ tab, const float* __restrict__ qsum,
         float* __restrict__ out, int N, float invNB) {
    const int tid = threadIdx.x;
    const int b   = blockIdx.y;
    const int sub = blockIdx.x;
    const int n   = sub * PPB + tid;

    const float4* __restrict__ T = tab + (size_t)b * KOBJ;   // block-uniform base

    float acc_tot = 0.f;
    if (n < N) {
        const float2 xy = *(const float2*)&cc[((size_t)b * N + n) * 2];
        const float bc = fminf(fmaxf(beta[(size_t)b * N + n], 1e-6f), 1.0f - 1e-5f);
        const int t = t_idx[(size_t)b * N + n];
        const float a = atanhf(bc / 1.002f);
        const float qn = a * a + QMIN;
        const float pn2e = fmaf(xy.x, xy.x, fmaf(xy.y, xy.y, 1e-6f));  // |p|^2 + eps

        float acc0 = 0.f, acc1 = 0.f;          // 2 independent chains
        #pragma unroll 16
        for (int k = 0; k < KOBJ; k += 2) {
            const float4 Ta = T[k];
            const float4 Tb = T[k + 1];
            const float d2a = fmaf(Ta.x, xy.x, fmaf(Ta.y, xy.y, Ta.z + pn2e));
            const float d2b = fmaf(Tb.x, xy.x, fmaf(Tb.y, xy.y, Tb.z + pn2e));
            const float da  = __builtin_amdgcn_sqrtf(d2a);
            const float db  = __builtin_amdgcn_sqrtf(d2b);
            acc0 = fmaf(Ta.w, fminf(da, 1.f), acc0);
            acc1 = fmaf(Tb.w, fminf(db, 1.f), acc1);
        }
        const float acc = acc0 + acc1;         // sum_k q_k * min(d_k, 1)

        // sum_k q_k*max(0,1-d_k) = qsum - acc; patch k==t: attractive d2 instead
        const float4 Tt = T[t];
        const float d2et = fmaf(Tt.x, xy.x, fmaf(Tt.y, xy.y, Tt.z + pn2e));
        const float dt   = __builtin_amdgcn_sqrtf(d2et);
        const float point = qsum[b] - acc
                          + Tt.w * ((d2et - 1e-6f) - 1.f + fminf(dt, 1.f));
        acc_tot = point * qn;
    }

    acc_tot = waveRedF(acc_tot);
    __shared__ float s_a[PPB / 64];
    if ((tid & 63) == 0) s_a[tid >> 6] = acc_tot;
    __syncthreads();
    if (tid == 0) {
        float s = 0.f;
        #pragma unroll
        for (int w = 0; w < PPB / 64; ++w) s += s_a[w];
        atomicAdd(out, s * invNB);             // device-scope, no fence needed
    }
}

extern "C" void kernel_launch(void* const* d_in, const int* in_sizes, int n_in,
                              void* d_out, int out_size, void* d_ws, size_t ws_size,
                              hipStream_t stream) {
    const float* cc   = (const float*)d_in[0];   // (B,N,2) f32
    const float* beta = (const float*)d_in[1];   // (B,N)   f32
    const int*   tix  = (const int*)d_in[2];     // (B,N)   i32
    float* out = (float*)d_out;
    const int N = in_sizes[1] / BATCH;

    char* ws = (char*)d_ws;
    u64*    pkey = (u64*)(ws + 0);
    float*  nsp  = (float*)(ws + 1048576);
    u32*    ncp  = (u32*)(ws + 1052672);
    float4* tab  = (float4*)(ws + 1056768);
    float*  qsum = (float*)(ws + 1073152);

    const int nppb = (N + PPB - 1) / PPB;        // pairs blocks per batch
    const float invNB = 1.f / ((float)N * (float)BATCH);

    oc_scan  <<<dim3(NSCB, BATCH), BDIM, 0, stream>>>(beta, tix, pkey, nsp, ncp, out, N);
    oc_reduce<<<dim3(BATCH), KOBJ, 0, stream>>>(cc, pkey, nsp, ncp, tab, qsum, out, N);
    oc_pairs <<<dim3(nppb, BATCH), PPB, 0, stream>>>(cc, beta, tix, tab, qsum, out, N, invNB);
}